// Round 3
// baseline (668.724 us; speedup 1.0000x reference)
//
#include <hip/hip_runtime.h>

#define NTOT 262144   // B*L
#define NLAY 8
#define TOUT 240      // output nodes per block (256 LDS nodes - 2*8 halo)

__device__ __forceinline__ float silu_f(float x) {
    return x * (1.0f / (1.0f + __expf(-x)));
}

// ---------------- Fully fused: encode + 8-layer SE3 stack + mid + decode ---
// One block owns window [g0-8, g0+248). Encode h0/pos0 from raw inputs
// (per-lane row streaming), run 8 layers + mid-latent in LDS, decode the
// 240 valid nodes straight to d_out. No intermediates, one launch.
__global__ __launch_bounds__(256) void k_fused(
    const float* __restrict__ ap, const float* __restrict__ amask,
    const float* __restrict__ embW, const float* __restrict__ embB,
    const float* __restrict__ peW1, const float* __restrict__ peB1,
    const float* __restrict__ peW2, const float* __restrict__ peB2,
    const float* __restrict__ ceW1, const float* __restrict__ ceB1,
    const float* __restrict__ ceW2, const float* __restrict__ ceB2,
    const float* __restrict__ cpW1, const float* __restrict__ cpB1,
    const float* __restrict__ cpW2,
    const float* __restrict__ cnW1, const float* __restrict__ cnB1,
    const float* __restrict__ cnW2, const float* __restrict__ cnB2,
    const float* __restrict__ tW1, const float* __restrict__ tB1,
    const float* __restrict__ tW2, const float* __restrict__ tB2,
    const float* __restrict__ fW1, const float* __restrict__ fB1,
    const float* __restrict__ fW2, const float* __restrict__ fB2,
    const float* __restrict__ dW1, const float* __restrict__ dB1,
    const float* __restrict__ dW2, const float* __restrict__ dB2,
    const float* __restrict__ mW, const float* __restrict__ mB,
    float* __restrict__ out)
{
    __shared__ float4 sH[512];               // 256 nodes x 8 f32 (8 KB)
    __shared__ float4 sP[256];               // 256 nodes x (3+pad)  (4 KB)
    __shared__ alignas(16) char SC[15360];   // scratch union (15 KB)
    float4* sE = (float4*)SC;                // 512 f4 (8 KB)  layer phase
    float4* sD = (float4*)(SC + 8192);       // 256 f4 (4 KB)  layer phase
    float*  st1 = (float*)SC;                // 240*16 f32     decode phase
    float*  sW  = (float*)SC;                // 37*8 f32       encode phase

    const int t = threadIdx.x;
    const int g0 = blockIdx.x * TOUT;
    const int g = g0 - 8 + t;
    const bool vg = (g >= 0 && g < NTOT);

    // ---- encode phase ----
    if (t < 74) ((float4*)sW)[t] = ((const float4*)embW)[t];
    __syncthreads();

    float hacc[8] = {0, 0, 0, 0, 0, 0, 0, 0};
    float ps0 = 0.f, ps1 = 0.f, ps2 = 0.f, msum = 0.f;
    if (vg) {
        const float* mrow = amask + (long)g * 37;
        const float* arow = ap + (long)g * 111;
        #pragma unroll 2
        for (int k = 0; k < 37; ++k) {
            float mv = mrow[k];
            msum += mv;
            const float4* wr = (const float4*)(sW + k * 8);
            float4 w0 = wr[0], w1 = wr[1];
            hacc[0] += mv * w0.x; hacc[1] += mv * w0.y;
            hacc[2] += mv * w0.z; hacc[3] += mv * w0.w;
            hacc[4] += mv * w1.x; hacc[5] += mv * w1.y;
            hacc[6] += mv * w1.z; hacc[7] += mv * w1.w;
            ps0 += mv * arow[k * 3 + 0];
            ps1 += mv * arow[k * 3 + 1];
            ps2 += mv * arow[k * 3 + 2];
        }
    }
    float inv = 1.0f / (msum + 1e-8f);
    float mp0 = ps0 * inv, mp1 = ps1 * inv, mp2 = ps2 * inv;
    {
        float q[8];
        #pragma unroll
        for (int j = 0; j < 8; ++j) {
            float a = peB1[j];
            a += mp0 * peW1[0 * 8 + j];
            a += mp1 * peW1[1 * 8 + j];
            a += mp2 * peW1[2 * 8 + j];
            q[j] = silu_f(a);
        }
        #pragma unroll
        for (int j = 0; j < 8; ++j) {
            float a = peB2[j] + embB[j];
            #pragma unroll
            for (int r = 0; r < 8; ++r) a += q[r] * peW2[r * 8 + j];
            hacc[j] += a;
        }
    }
    __syncthreads();   // sW reads done before sE overwrites
    if (vg) {
        sH[t * 2]     = make_float4(hacc[0], hacc[1], hacc[2], hacc[3]);
        sH[t * 2 + 1] = make_float4(hacc[4], hacc[5], hacc[6], hacc[7]);
        sP[t] = make_float4(mp0, mp1, mp2, 0.f);
    } else {
        float4 z = make_float4(0.f, 0.f, 0.f, 0.f);
        sH[t * 2] = z; sH[t * 2 + 1] = z; sP[t] = z;
    }
    __syncthreads();

    // ---- 8-layer stack ----
    const int tp = (t < 255) ? (t + 1) : t;
    const int tm = (t > 0) ? (t - 1) : t;
    float hn[8] = {0, 0, 0, 0, 0, 0, 0, 0};

    #pragma unroll 1
    for (int li = 0; li < NLAY; ++li) {
        float hl[8], hr[8];
        {
            float4 a = sH[t * 2], b = sH[t * 2 + 1];
            hl[0] = a.x; hl[1] = a.y; hl[2] = a.z; hl[3] = a.w;
            hl[4] = b.x; hl[5] = b.y; hl[6] = b.z; hl[7] = b.w;
            float4 c = sH[tp * 2], d = sH[tp * 2 + 1];
            hr[0] = c.x; hr[1] = c.y; hr[2] = c.z; hr[3] = c.w;
            hr[4] = d.x; hr[5] = d.y; hr[6] = d.z; hr[7] = d.w;
        }
        float4 plv = sP[t], prv = sP[tp];
        float r0 = prv.x - plv.x, r1 = prv.y - plv.y, r2 = prv.z - plv.z;
        float dist = sqrtf(r0 * r0 + r1 * r1 + r2 * r2);

        const float* wE1 = ceW1 + li * 136;
        const float* bE1 = ceB1 + li * 8;
        const float* wE2 = ceW2 + li * 64;
        const float* bE2 = ceB2 + li * 8;
        const float* wP1 = cpW1 + li * 64;
        const float* bP1 = cpB1 + li * 8;
        const float* wP2 = cpW2 + li * 24;
        const float* wN1 = cnW1 + li * 128;
        const float* bN1 = cnB1 + li * 8;
        const float* wN2 = cnW2 + li * 64;
        const float* bN2 = cnB2 + li * 8;

        float t1[8];
        #pragma unroll
        for (int j = 0; j < 8; ++j) {
            float a = bE1[j];
            #pragma unroll
            for (int r = 0; r < 8; ++r) a += hl[r] * wE1[r * 8 + j];
            #pragma unroll
            for (int r = 0; r < 8; ++r) a += hr[r] * wE1[64 + r * 8 + j];
            a += dist * wE1[128 + j];
            t1[j] = silu_f(a);
        }
        float ea[8];
        #pragma unroll
        for (int j = 0; j < 8; ++j) {
            float a = bE2[j];
            #pragma unroll
            for (int r = 0; r < 8; ++r) a += t1[r] * wE2[r * 8 + j];
            ea[j] = a;
        }
        float q[8];
        #pragma unroll
        for (int j = 0; j < 8; ++j) {
            float a = bP1[j];
            #pragma unroll
            for (int r = 0; r < 8; ++r) a += ea[r] * wP1[r * 8 + j];
            q[j] = silu_f(a);
        }
        float dp0 = 0.f, dp1 = 0.f, dp2 = 0.f;
        #pragma unroll
        for (int r = 0; r < 8; ++r) {
            dp0 += q[r] * wP2[r * 3 + 0];
            dp1 += q[r] * wP2[r * 3 + 1];
            dp2 += q[r] * wP2[r * 3 + 2];
        }
        sE[t * 2] = make_float4(ea[0], ea[1], ea[2], ea[3]);
        sE[t * 2 + 1] = make_float4(ea[4], ea[5], ea[6], ea[7]);
        sD[t] = make_float4(dp0, dp1, dp2, 0.f);
        __syncthreads();

        float nu[8] = {0, 0, 0, 0, 0, 0, 0, 0};
        float pu0 = 0.f, pu1 = 0.f, pu2 = 0.f;
        if (g < NTOT - 1) {
            #pragma unroll
            for (int j = 0; j < 8; ++j) nu[j] += ea[j];
            pu0 += dp0; pu1 += dp1; pu2 += dp2;
        }
        if (g > 0) {
            float4 a = sE[tm * 2], b = sE[tm * 2 + 1];
            nu[0] += a.x; nu[1] += a.y; nu[2] += a.z; nu[3] += a.w;
            nu[4] += b.x; nu[5] += b.y; nu[6] += b.z; nu[7] += b.w;
            float4 dl = sD[tm];
            pu0 -= dl.x; pu1 -= dl.y; pu2 -= dl.z;
        }
        float u[8];
        #pragma unroll
        for (int j = 0; j < 8; ++j) {
            float a = bN1[j];
            #pragma unroll
            for (int r = 0; r < 8; ++r) a += hl[r] * wN1[r * 8 + j];
            #pragma unroll
            for (int r = 0; r < 8; ++r) a += nu[r] * wN1[64 + r * 8 + j];
            u[j] = silu_f(a);
        }
        #pragma unroll
        for (int j = 0; j < 8; ++j) {
            float a = bN2[j];
            #pragma unroll
            for (int r = 0; r < 8; ++r) a += u[r] * wN2[r * 8 + j];
            hn[j] = a;
        }
        float pn0 = plv.x + 0.1f * pu0;
        float pn1 = plv.y + 0.1f * pu1;
        float pn2 = plv.z + 0.1f * pu2;

        if (li == 3) {  // mid latent: tol then froml
            float a8[8];
            #pragma unroll
            for (int j = 0; j < 8; ++j) {
                float a = tB1[j];
                #pragma unroll
                for (int r = 0; r < 8; ++r) a += hn[r] * tW1[r * 8 + j];
                a8[j] = silu_f(a);
            }
            float zz[8];
            #pragma unroll
            for (int j = 0; j < 8; ++j) {
                float a = tB2[j];
                #pragma unroll
                for (int r = 0; r < 8; ++r) a += a8[r] * tW2[r * 8 + j];
                zz[j] = a;
            }
            float b8[8];
            #pragma unroll
            for (int j = 0; j < 8; ++j) {
                float a = fB1[j];
                #pragma unroll
                for (int r = 0; r < 8; ++r) a += zz[r] * fW1[r * 8 + j];
                b8[j] = silu_f(a);
            }
            #pragma unroll
            for (int j = 0; j < 8; ++j) {
                float a = fB2[j];
                #pragma unroll
                for (int r = 0; r < 8; ++r) a += b8[r] * fW2[r * 8 + j];
                hn[j] = a;
            }
        }

        const int winLo2 = max(0, g0 - 7 + li);
        const int winHi2 = min(NTOT, g0 + 247 - li);
        if (g >= winLo2 && g < winHi2) {
            sH[t * 2] = make_float4(hn[0], hn[1], hn[2], hn[3]);
            sH[t * 2 + 1] = make_float4(hn[4], hn[5], hn[6], hn[7]);
            sP[t] = make_float4(pn0, pn1, pn2, 0.f);
        }
        __syncthreads();
    }
    // sH[w+8] now holds final h for window node w in [0,240) (g0+w < NTOT)

    // ---- decode phase ----
    // st1 = silu(h @ posdec_W1 + b1), 2 thread-tasks per node
    #pragma unroll 1
    for (int idx = t; idx < 480; idx += 256) {
        const int w = idx >> 1;
        const int c0 = (idx & 1) * 8;
        if (g0 + w < NTOT) {
            const float4* h4 = (const float4*)&sH[(w + 8) * 2];
            float4 h0v = h4[0], h1v = h4[1];
            float hr[8] = {h0v.x, h0v.y, h0v.z, h0v.w, h1v.x, h1v.y, h1v.z, h1v.w};
            #pragma unroll
            for (int jj = 0; jj < 8; ++jj) {
                int j = c0 + jj;
                float a = dB1[j];
                #pragma unroll
                for (int r = 0; r < 8; ++r) a += hr[r] * dW1[r * 16 + j];
                st1[w * 16 + j] = silu_f(a);
            }
        }
    }
    __syncthreads();

    if (t < 222) {
        // pos_out: column-stationary
        const int half = (t >= 111) ? 1 : 0;
        const int j = t - half * 111;
        float w[16];
        #pragma unroll
        for (int r = 0; r < 16; ++r) w[r] = dW2[r * 111 + j];
        const float bj = dB2[j];
        float* op = out + (long)g0 * 111 + j;
        #pragma unroll 2
        for (int n = half; n < TOUT; n += 2) {
            if (g0 + n >= NTOT) break;
            const float4* t4 = (const float4*)(st1 + n * 16);
            float4 a0 = t4[0], a1 = t4[1], a2 = t4[2], a3 = t4[3];
            float acc = bj;
            acc += a0.x * w[0] + a0.y * w[1] + a0.z * w[2] + a0.w * w[3];
            acc += a1.x * w[4] + a1.y * w[5] + a1.z * w[6] + a1.w * w[7];
            acc += a2.x * w[8] + a2.y * w[9] + a2.z * w[10] + a2.w * w[11];
            acc += a3.x * w[12] + a3.y * w[13] + a3.z * w[14] + a3.w * w[15];
            op[n * 111] = acc;
        }
        // mask_out: column-stationary
        const int g6 = t / 37;        // 0..5
        const int j2 = t - g6 * 37;
        float wm[8];
        #pragma unroll
        for (int r = 0; r < 8; ++r) wm[r] = mW[r * 37 + j2];
        const float bm = mB[j2];
        float* omp_ = out + (long)NTOT * 111 + (long)g0 * 37 + j2;
        #pragma unroll 1
        for (int n = g6; n < TOUT; n += 6) {
            if (g0 + n >= NTOT) break;
            const float4* h4 = (const float4*)&sH[(n + 8) * 2];
            float4 h0v = h4[0], h1v = h4[1];
            float acc = bm;
            acc += h0v.x * wm[0] + h0v.y * wm[1] + h0v.z * wm[2] + h0v.w * wm[3];
            acc += h1v.x * wm[4] + h1v.y * wm[5] + h1v.z * wm[6] + h1v.w * wm[7];
            omp_[n * 37] = acc;
        }
    }
}

extern "C" void kernel_launch(void* const* d_in, const int* in_sizes, int n_in,
                              void* d_out, int out_size, void* d_ws, size_t ws_size,
                              hipStream_t stream) {
    const float* ap     = (const float*)d_in[0];
    const float* amask  = (const float*)d_in[1];
    const float* embW   = (const float*)d_in[2];
    const float* embB   = (const float*)d_in[3];
    const float* peW1   = (const float*)d_in[4];
    const float* peB1   = (const float*)d_in[5];
    const float* peW2   = (const float*)d_in[6];
    const float* peB2   = (const float*)d_in[7];
    const float* ceW1   = (const float*)d_in[8];
    const float* ceB1   = (const float*)d_in[9];
    const float* ceW2   = (const float*)d_in[10];
    const float* ceB2   = (const float*)d_in[11];
    const float* cpW1   = (const float*)d_in[12];
    const float* cpB1   = (const float*)d_in[13];
    const float* cpW2   = (const float*)d_in[14];
    const float* cnW1   = (const float*)d_in[15];
    const float* cnB1   = (const float*)d_in[16];
    const float* cnW2   = (const float*)d_in[17];
    const float* cnB2   = (const float*)d_in[18];
    const float* tW1    = (const float*)d_in[19];
    const float* tB1    = (const float*)d_in[20];
    const float* tW2    = (const float*)d_in[21];
    const float* tB2    = (const float*)d_in[22];
    const float* fW1    = (const float*)d_in[23];
    const float* fB1    = (const float*)d_in[24];
    const float* fW2    = (const float*)d_in[25];
    const float* fB2    = (const float*)d_in[26];
    const float* dW1    = (const float*)d_in[27];
    const float* dB1    = (const float*)d_in[28];
    const float* dW2    = (const float*)d_in[29];
    const float* dB2    = (const float*)d_in[30];
    const float* mW     = (const float*)d_in[31];
    const float* mB     = (const float*)d_in[32];
    float* out = (float*)d_out;

    const int nblk = (NTOT + TOUT - 1) / TOUT;
    k_fused<<<nblk, 256, 0, stream>>>(
        ap, amask, embW, embB, peW1, peB1, peW2, peB2,
        ceW1, ceB1, ceW2, ceB2, cpW1, cpB1, cpW2,
        cnW1, cnB1, cnW2, cnB2,
        tW1, tB1, tW2, tB2, fW1, fB1, fW2, fB2,
        dW1, dB1, dW2, dB2, mW, mB, out);
}

// Round 4
// 483.587 us; speedup vs baseline: 1.3828x; 1.3828x over previous
//
#include <hip/hip_runtime.h>

#define NTOT 262144   // B*L
#define NLAY 8
#define TOUT 240      // output nodes per block (256 LDS nodes - 2*8 halo)
#define CHUNK 32      // encode staging chunk (nodes)
#define NCH 8         // 256 / CHUNK

__device__ __forceinline__ float silu_f(float x) {
    return x * __builtin_amdgcn_rcpf(1.0f + __expf(-x));
}

// ---------------- Fully fused: encode + 8-layer SE3 stack + mid + decode ---
// One block owns window [g0-8, g0+248). Encode stages raw inputs through LDS
// in 32-node chunks (coalesced float4), 8 lanes/node shuffle-reduce; then the
// 8-layer stack runs in LDS; decode streams straight to d_out.
__global__ __launch_bounds__(256) void k_fused(
    const float* __restrict__ ap, const float* __restrict__ amask,
    const float* __restrict__ embW, const float* __restrict__ embB,
    const float* __restrict__ peW1, const float* __restrict__ peB1,
    const float* __restrict__ peW2, const float* __restrict__ peB2,
    const float* __restrict__ ceW1, const float* __restrict__ ceB1,
    const float* __restrict__ ceW2, const float* __restrict__ ceB2,
    const float* __restrict__ cpW1, const float* __restrict__ cpB1,
    const float* __restrict__ cpW2,
    const float* __restrict__ cnW1, const float* __restrict__ cnB1,
    const float* __restrict__ cnW2, const float* __restrict__ cnB2,
    const float* __restrict__ tW1, const float* __restrict__ tB1,
    const float* __restrict__ tW2, const float* __restrict__ tB2,
    const float* __restrict__ fW1, const float* __restrict__ fB1,
    const float* __restrict__ fW2, const float* __restrict__ fB2,
    const float* __restrict__ dW1, const float* __restrict__ dB1,
    const float* __restrict__ dW2, const float* __restrict__ dB2,
    const float* __restrict__ mW, const float* __restrict__ mB,
    float* __restrict__ out)
{
    __shared__ float4 sH[512];               // 256 nodes x 8 f32 (8 KB)
    __shared__ float4 sP[256];               // 256 nodes x (3+pad)  (4 KB)
    __shared__ alignas(16) float sW[296];    // embW staged (1.2 KB)
    __shared__ alignas(16) char SC[18944];   // scratch union (18.5 KB)
    // encode phase: mask stage (4736 B) + pos stage (14208 B)
    float4* sMk = (float4*)SC;               // 296 f4
    float4* sPs = (float4*)(SC + 4736);      // 888 f4
    // layer phase:
    float4* sE = (float4*)SC;                // 512 f4 (8 KB)
    float4* sD = (float4*)(SC + 8192);       // 256 f4 (4 KB)
    // decode phase:
    float*  st1 = (float*)SC;                // 240*16 f32 (15 KB)

    const int t = threadIdx.x;
    const int g0 = blockIdx.x * TOUT;
    const int g = g0 - 8 + t;
    const bool vg = (g >= 0 && g < NTOT);
    const float4 z4 = make_float4(0.f, 0.f, 0.f, 0.f);

    if (t < 74) ((float4*)sW)[t] = ((const float4*)embW)[t];

    // ---- encode: 8 chunks of 32 nodes, coalesced staging + 8-lane reduce ----
    const int w = t >> 3;       // node within chunk
    const int p = t & 7;        // lane within node-group
    #pragma unroll 1
    for (int c = 0; c < NCH; ++c) {
        const int gbase = g0 - 8 + c * CHUNK;          // multiple of 4 (may be <0)
        const int mb4 = (gbase >> 2) * 37;
        const int pb4 = (gbase >> 2) * 111;
        #pragma unroll
        for (int i = 0; i < 2; ++i) {                  // 296 float4
            int ii = t + i * 256;
            if (ii < 296) {
                int idx = mb4 + ii;
                sMk[ii] = (idx >= 0 && idx < NTOT * 37 / 4)
                          ? ((const float4*)amask)[idx] : z4;
            }
        }
        #pragma unroll
        for (int i = 0; i < 4; ++i) {                  // 888 float4
            int ii = t + i * 256;
            if (ii < 888) {
                int idx = pb4 + ii;
                sPs[ii] = (idx >= 0 && idx < NTOT * 111 / 4)
                          ? ((const float4*)ap)[idx] : z4;
            }
        }
        __syncthreads();

        const float* mrow = (const float*)sMk + w * 37;
        const float* arow = (const float*)sPs + w * 111;
        float hacc[8] = {0, 0, 0, 0, 0, 0, 0, 0};
        float ps0 = 0.f, ps1 = 0.f, ps2 = 0.f, msum = 0.f;
        #pragma unroll 1
        for (int k = p; k < 37; k += 8) {
            float mv = mrow[k];
            msum += mv;
            const float4 w0 = ((const float4*)sW)[k * 2];
            const float4 w1 = ((const float4*)sW)[k * 2 + 1];
            hacc[0] += mv * w0.x; hacc[1] += mv * w0.y;
            hacc[2] += mv * w0.z; hacc[3] += mv * w0.w;
            hacc[4] += mv * w1.x; hacc[5] += mv * w1.y;
            hacc[6] += mv * w1.z; hacc[7] += mv * w1.w;
            ps0 += mv * arow[k * 3 + 0];
            ps1 += mv * arow[k * 3 + 1];
            ps2 += mv * arow[k * 3 + 2];
        }
        #pragma unroll
        for (int m = 1; m <= 4; m <<= 1) {
            msum += __shfl_xor(msum, m);
            ps0 += __shfl_xor(ps0, m);
            ps1 += __shfl_xor(ps1, m);
            ps2 += __shfl_xor(ps2, m);
            #pragma unroll
            for (int j = 0; j < 8; ++j) hacc[j] += __shfl_xor(hacc[j], m);
        }
        const int widx = c * CHUNK + w;
        const int gn = g0 - 8 + widx;
        const bool val = (gn >= 0 && gn < NTOT);
        float inv = __builtin_amdgcn_rcpf(msum + 1e-8f);
        float mp0 = ps0 * inv, mp1 = ps1 * inv, mp2 = ps2 * inv;
        if (p == 0) sH[widx * 2]     = val ? make_float4(hacc[0], hacc[1], hacc[2], hacc[3]) : z4;
        if (p == 1) sH[widx * 2 + 1] = val ? make_float4(hacc[4], hacc[5], hacc[6], hacc[7]) : z4;
        if (p == 2) sP[widx]         = val ? make_float4(mp0, mp1, mp2, 0.f) : z4;
        __syncthreads();
    }

    // ---- per-node pos-feat MLP + biases (once per node) ----
    {
        float4 pv = sP[t];
        float q[8];
        #pragma unroll
        for (int j = 0; j < 8; ++j) {
            float a = peB1[j];
            a += pv.x * peW1[0 * 8 + j];
            a += pv.y * peW1[1 * 8 + j];
            a += pv.z * peW1[2 * 8 + j];
            q[j] = silu_f(a);
        }
        float add[8];
        #pragma unroll
        for (int j = 0; j < 8; ++j) {
            float a = peB2[j] + embB[j];
            #pragma unroll
            for (int r = 0; r < 8; ++r) a += q[r] * peW2[r * 8 + j];
            add[j] = a;
        }
        if (vg) {
            float4 a = sH[t * 2], b = sH[t * 2 + 1];
            a.x += add[0]; a.y += add[1]; a.z += add[2]; a.w += add[3];
            b.x += add[4]; b.y += add[5]; b.z += add[6]; b.w += add[7];
            sH[t * 2] = a;
            sH[t * 2 + 1] = b;
        }
    }
    __syncthreads();

    // ---- 8-layer stack ----
    const int tp = (t < 255) ? (t + 1) : t;
    const int tm = (t > 0) ? (t - 1) : t;
    float hn[8] = {0, 0, 0, 0, 0, 0, 0, 0};

    #pragma unroll 1
    for (int li = 0; li < NLAY; ++li) {
        float hl[8], hr[8];
        {
            float4 a = sH[t * 2], b = sH[t * 2 + 1];
            hl[0] = a.x; hl[1] = a.y; hl[2] = a.z; hl[3] = a.w;
            hl[4] = b.x; hl[5] = b.y; hl[6] = b.z; hl[7] = b.w;
            float4 c = sH[tp * 2], d = sH[tp * 2 + 1];
            hr[0] = c.x; hr[1] = c.y; hr[2] = c.z; hr[3] = c.w;
            hr[4] = d.x; hr[5] = d.y; hr[6] = d.z; hr[7] = d.w;
        }
        float4 plv = sP[t], prv = sP[tp];
        float r0 = prv.x - plv.x, r1 = prv.y - plv.y, r2 = prv.z - plv.z;
        float dist = sqrtf(r0 * r0 + r1 * r1 + r2 * r2);

        const float* wE1 = ceW1 + li * 136;
        const float* bE1 = ceB1 + li * 8;
        const float* wE2 = ceW2 + li * 64;
        const float* bE2 = ceB2 + li * 8;
        const float* wP1 = cpW1 + li * 64;
        const float* bP1 = cpB1 + li * 8;
        const float* wP2 = cpW2 + li * 24;
        const float* wN1 = cnW1 + li * 128;
        const float* bN1 = cnB1 + li * 8;
        const float* wN2 = cnW2 + li * 64;
        const float* bN2 = cnB2 + li * 8;

        float t1[8];
        #pragma unroll
        for (int j = 0; j < 8; ++j) {
            float a = bE1[j];
            #pragma unroll
            for (int r = 0; r < 8; ++r) a += hl[r] * wE1[r * 8 + j];
            #pragma unroll
            for (int r = 0; r < 8; ++r) a += hr[r] * wE1[64 + r * 8 + j];
            a += dist * wE1[128 + j];
            t1[j] = silu_f(a);
        }
        float ea[8];
        #pragma unroll
        for (int j = 0; j < 8; ++j) {
            float a = bE2[j];
            #pragma unroll
            for (int r = 0; r < 8; ++r) a += t1[r] * wE2[r * 8 + j];
            ea[j] = a;
        }
        float q[8];
        #pragma unroll
        for (int j = 0; j < 8; ++j) {
            float a = bP1[j];
            #pragma unroll
            for (int r = 0; r < 8; ++r) a += ea[r] * wP1[r * 8 + j];
            q[j] = silu_f(a);
        }
        float dp0 = 0.f, dp1 = 0.f, dp2 = 0.f;
        #pragma unroll
        for (int r = 0; r < 8; ++r) {
            dp0 += q[r] * wP2[r * 3 + 0];
            dp1 += q[r] * wP2[r * 3 + 1];
            dp2 += q[r] * wP2[r * 3 + 2];
        }
        sE[t * 2] = make_float4(ea[0], ea[1], ea[2], ea[3]);
        sE[t * 2 + 1] = make_float4(ea[4], ea[5], ea[6], ea[7]);
        sD[t] = make_float4(dp0, dp1, dp2, 0.f);
        __syncthreads();

        float nu[8] = {0, 0, 0, 0, 0, 0, 0, 0};
        float pu0 = 0.f, pu1 = 0.f, pu2 = 0.f;
        if (g < NTOT - 1) {
            #pragma unroll
            for (int j = 0; j < 8; ++j) nu[j] += ea[j];
            pu0 += dp0; pu1 += dp1; pu2 += dp2;
        }
        if (g > 0) {
            float4 a = sE[tm * 2], b = sE[tm * 2 + 1];
            nu[0] += a.x; nu[1] += a.y; nu[2] += a.z; nu[3] += a.w;
            nu[4] += b.x; nu[5] += b.y; nu[6] += b.z; nu[7] += b.w;
            float4 dl = sD[tm];
            pu0 -= dl.x; pu1 -= dl.y; pu2 -= dl.z;
        }
        float u[8];
        #pragma unroll
        for (int j = 0; j < 8; ++j) {
            float a = bN1[j];
            #pragma unroll
            for (int r = 0; r < 8; ++r) a += hl[r] * wN1[r * 8 + j];
            #pragma unroll
            for (int r = 0; r < 8; ++r) a += nu[r] * wN1[64 + r * 8 + j];
            u[j] = silu_f(a);
        }
        #pragma unroll
        for (int j = 0; j < 8; ++j) {
            float a = bN2[j];
            #pragma unroll
            for (int r = 0; r < 8; ++r) a += u[r] * wN2[r * 8 + j];
            hn[j] = a;
        }
        float pn0 = plv.x + 0.1f * pu0;
        float pn1 = plv.y + 0.1f * pu1;
        float pn2 = plv.z + 0.1f * pu2;

        if (li == 3) {  // mid latent: tol then froml
            float a8[8];
            #pragma unroll
            for (int j = 0; j < 8; ++j) {
                float a = tB1[j];
                #pragma unroll
                for (int r = 0; r < 8; ++r) a += hn[r] * tW1[r * 8 + j];
                a8[j] = silu_f(a);
            }
            float zz[8];
            #pragma unroll
            for (int j = 0; j < 8; ++j) {
                float a = tB2[j];
                #pragma unroll
                for (int r = 0; r < 8; ++r) a += a8[r] * tW2[r * 8 + j];
                zz[j] = a;
            }
            float b8[8];
            #pragma unroll
            for (int j = 0; j < 8; ++j) {
                float a = fB1[j];
                #pragma unroll
                for (int r = 0; r < 8; ++r) a += zz[r] * fW1[r * 8 + j];
                b8[j] = silu_f(a);
            }
            #pragma unroll
            for (int j = 0; j < 8; ++j) {
                float a = fB2[j];
                #pragma unroll
                for (int r = 0; r < 8; ++r) a += b8[r] * fW2[r * 8 + j];
                hn[j] = a;
            }
        }

        const int winLo2 = max(0, g0 - 7 + li);
        const int winHi2 = min(NTOT, g0 + 247 - li);
        if (g >= winLo2 && g < winHi2) {
            sH[t * 2] = make_float4(hn[0], hn[1], hn[2], hn[3]);
            sH[t * 2 + 1] = make_float4(hn[4], hn[5], hn[6], hn[7]);
            sP[t] = make_float4(pn0, pn1, pn2, 0.f);
        }
        __syncthreads();
    }
    // sH[w+8] now holds final h for window node w in [0,240)

    // ---- decode phase ----
    #pragma unroll 1
    for (int idx = t; idx < 480; idx += 256) {
        const int w2 = idx >> 1;
        const int c0 = (idx & 1) * 8;
        if (g0 + w2 < NTOT) {
            const float4* h4 = (const float4*)&sH[(w2 + 8) * 2];
            float4 h0v = h4[0], h1v = h4[1];
            float hr[8] = {h0v.x, h0v.y, h0v.z, h0v.w, h1v.x, h1v.y, h1v.z, h1v.w};
            #pragma unroll
            for (int jj = 0; jj < 8; ++jj) {
                int j = c0 + jj;
                float a = dB1[j];
                #pragma unroll
                for (int r = 0; r < 8; ++r) a += hr[r] * dW1[r * 16 + j];
                st1[w2 * 16 + j] = silu_f(a);
            }
        }
    }
    __syncthreads();

    if (t < 222) {
        // pos_out: column-stationary
        const int half = (t >= 111) ? 1 : 0;
        const int j = t - half * 111;
        float wv[16];
        #pragma unroll
        for (int r = 0; r < 16; ++r) wv[r] = dW2[r * 111 + j];
        const float bj = dB2[j];
        float* op = out + (long)g0 * 111 + j;
        #pragma unroll 2
        for (int n = half; n < TOUT; n += 2) {
            if (g0 + n >= NTOT) break;
            const float4* t4 = (const float4*)(st1 + n * 16);
            float4 a0 = t4[0], a1 = t4[1], a2 = t4[2], a3 = t4[3];
            float acc = bj;
            acc += a0.x * wv[0] + a0.y * wv[1] + a0.z * wv[2] + a0.w * wv[3];
            acc += a1.x * wv[4] + a1.y * wv[5] + a1.z * wv[6] + a1.w * wv[7];
            acc += a2.x * wv[8] + a2.y * wv[9] + a2.z * wv[10] + a2.w * wv[11];
            acc += a3.x * wv[12] + a3.y * wv[13] + a3.z * wv[14] + a3.w * wv[15];
            op[n * 111] = acc;
        }
        // mask_out: column-stationary
        const int g6 = t / 37;        // 0..5
        const int j2 = t - g6 * 37;
        float wm[8];
        #pragma unroll
        for (int r = 0; r < 8; ++r) wm[r] = mW[r * 37 + j2];
        const float bm = mB[j2];
        float* omp_ = out + (long)NTOT * 111 + (long)g0 * 37 + j2;
        #pragma unroll 1
        for (int n = g6; n < TOUT; n += 6) {
            if (g0 + n >= NTOT) break;
            const float4* h4 = (const float4*)&sH[(n + 8) * 2];
            float4 h0v = h4[0], h1v = h4[1];
            float acc = bm;
            acc += h0v.x * wm[0] + h0v.y * wm[1] + h0v.z * wm[2] + h0v.w * wm[3];
            acc += h1v.x * wm[4] + h1v.y * wm[5] + h1v.z * wm[6] + h1v.w * wm[7];
            omp_[n * 37] = acc;
        }
    }
}

extern "C" void kernel_launch(void* const* d_in, const int* in_sizes, int n_in,
                              void* d_out, int out_size, void* d_ws, size_t ws_size,
                              hipStream_t stream) {
    const float* ap     = (const float*)d_in[0];
    const float* amask  = (const float*)d_in[1];
    const float* embW   = (const float*)d_in[2];
    const float* embB   = (const float*)d_in[3];
    const float* peW1   = (const float*)d_in[4];
    const float* peB1   = (const float*)d_in[5];
    const float* peW2   = (const float*)d_in[6];
    const float* peB2   = (const float*)d_in[7];
    const float* ceW1   = (const float*)d_in[8];
    const float* ceB1   = (const float*)d_in[9];
    const float* ceW2   = (const float*)d_in[10];
    const float* ceB2   = (const float*)d_in[11];
    const float* cpW1   = (const float*)d_in[12];
    const float* cpB1   = (const float*)d_in[13];
    const float* cpW2   = (const float*)d_in[14];
    const float* cnW1   = (const float*)d_in[15];
    const float* cnB1   = (const float*)d_in[16];
    const float* cnW2   = (const float*)d_in[17];
    const float* cnB2   = (const float*)d_in[18];
    const float* tW1    = (const float*)d_in[19];
    const float* tB1    = (const float*)d_in[20];
    const float* tW2    = (const float*)d_in[21];
    const float* tB2    = (const float*)d_in[22];
    const float* fW1    = (const float*)d_in[23];
    const float* fB1    = (const float*)d_in[24];
    const float* fW2    = (const float*)d_in[25];
    const float* fB2    = (const float*)d_in[26];
    const float* dW1    = (const float*)d_in[27];
    const float* dB1    = (const float*)d_in[28];
    const float* dW2    = (const float*)d_in[29];
    const float* dB2    = (const float*)d_in[30];
    const float* mW     = (const float*)d_in[31];
    const float* mB     = (const float*)d_in[32];
    float* out = (float*)d_out;

    const int nblk = (NTOT + TOUT - 1) / TOUT;
    k_fused<<<nblk, 256, 0, stream>>>(
        ap, amask, embW, embB, peW1, peB1, peW2, peB2,
        ceW1, ceB1, ceW2, ceB2, cpW1, cpB1, cpW2,
        cnW1, cnB1, cnW2, cnB2,
        tW1, tB1, tW2, tB2, fW1, fB1, fW2, fB2,
        dW1, dB1, dW2, dB2, mW, mB, out);
}